// Round 5
// baseline (1492.192 us; speedup 1.0000x reference)
//
#include <hip/hip_runtime.h>
#include <hip/hip_bf16.h>

typedef __hip_bfloat16 bf16;

#define R_NUM 40000
#define E_NUM 500000
#define DEG_CAP 192

// wbuf layout (f32 element offsets)
#define W_P1W 0
#define W_P1B 4096
#define W_APW 4160    // 2*128*64
#define W_APB 20544   // 2*64
#define W_ABIN 20672  // 2*10*8
#define W_AVEC 20832  // 2*8*8
#define W_AW 20960    // 2*64*64
#define W_AB 29152
#define W_RW 29280
#define W_RB 37472
#define W_END 37600

static __device__ __forceinline__ float b2f(bf16 x) { return __bfloat162float(x); }

static __device__ __forceinline__ float ldv(const float* p, size_t i) { return p[i]; }
static __device__ __forceinline__ float ldv(const bf16* p, size_t i) { return __bfloat162float(p[i]); }
static __device__ __forceinline__ void stv(float* p, size_t i, float v) { p[i] = v; }
static __device__ __forceinline__ void stv(bf16* p, size_t i, float v) { p[i] = __float2bfloat16(v); }

// ---------------- runtime dtype detection (robustness only) ----------------
// flag[0]: triplets int64 (odd 32-bit words all zero over 1024 samples)
// flag[1]: floats are f32 (even u16 words of rel_emb are random mantissa bits)

__global__ void k_detect(const unsigned int* __restrict__ trip_w,
                         const unsigned short* __restrict__ emb_w, int* __restrict__ flag) {
  int lane = threadIdx.x;
  unsigned int acc = 0;
  for (int i = lane; i < 1024; i += 64) acc |= trip_w[2 * i + 1];
  int votes = 0;
  for (int i = lane; i < 2048; i += 64) {
    unsigned short u = emb_w[2 * i];
    int ex = (u >> 7) & 0xFF;
    if (ex >= 90 && ex <= 130) votes++;
  }
  for (int off = 1; off < 64; off <<= 1) {
    acc |= __shfl_xor(acc, off);
    votes += __shfl_xor(votes, off);
  }
  if (lane == 0) {
    flag[0] = (acc == 0) ? 1 : 0;
    flag[1] = (votes < 1024) ? 1 : 0;
  }
}

// ---------------- weights -> f32 scratch ----------------

__global__ void k_wconv(const void* p1w, const void* p1b, const void* apw, const void* apb,
                        const void* abin, const void* avec, const void* aw, const void* ab,
                        const void* rw, const void* rb, const int* __restrict__ flag,
                        float* __restrict__ wbuf) {
  int i = blockIdx.x * 256 + threadIdx.x;
  if (i >= W_END) return;
  const void* src;
  int off;
  if (i < W_P1B) { src = p1w; off = i - W_P1W; }
  else if (i < W_APW) { src = p1b; off = i - W_P1B; }
  else if (i < W_APB) { src = apw; off = i - W_APW; }
  else if (i < W_ABIN) { src = apb; off = i - W_APB; }
  else if (i < W_AVEC) { src = abin; off = i - W_ABIN; }
  else if (i < W_AW) { src = avec; off = i - W_AVEC; }
  else if (i < W_AB) { src = aw; off = i - W_AW; }
  else if (i < W_RW) { src = ab; off = i - W_AB; }
  else if (i < W_RB) { src = rw; off = i - W_RW; }
  else { src = rb; off = i - W_RB; }
  wbuf[i] = flag[1] ? ((const float*)src)[off] : b2f(((const bf16*)src)[off]);
}

// ---------------- edge decode ----------------

static __device__ __forceinline__ void load_edge(const unsigned int* __restrict__ w, int e,
                                                 int i64, int& h, int& t, int& b) {
  if (i64) {
    h = (int)w[6 * e + 0];
    t = (int)w[6 * e + 2];
    b = (int)w[6 * e + 4];
  } else {
    h = (int)w[3 * e + 0];
    t = (int)w[3 * e + 1];
    b = (int)w[3 * e + 2];
  }
}

// ---------------- counting sort by head ----------------

__global__ void k_hist(const unsigned int* __restrict__ trip_w, const int* __restrict__ flag,
                       int* __restrict__ counts) {
  int e = blockIdx.x * 256 + threadIdx.x;
  if (e >= E_NUM) return;
  int h, t, b;
  load_edge(trip_w, e, flag[0], h, t, b);
  atomicAdd(&counts[h], 1);
}

__global__ void k_scan(const int* __restrict__ counts, int* __restrict__ row_ptr) {
  __shared__ int sd[1024];
  int tid = threadIdx.x;
  int carry = 0;
  for (int base = 0; base < 40960; base += 1024) {
    int idx = base + tid;
    int v = (idx < R_NUM) ? counts[idx] : 0;
    sd[tid] = v;
    __syncthreads();
    for (int off = 1; off < 1024; off <<= 1) {
      int t = (tid >= off) ? sd[tid - off] : 0;
      __syncthreads();
      sd[tid] += t;
      __syncthreads();
    }
    if (idx < R_NUM) row_ptr[idx] = carry + sd[tid] - v;  // exclusive
    carry += sd[1023];
    __syncthreads();
  }
  if (tid == 0) row_ptr[R_NUM] = carry;
}

// scatter bumps row_ptr: afterwards row_ptr[r] == end(r); beg(r) = r ? row_ptr[r-1] : 0
__global__ void k_scatter(const unsigned int* __restrict__ trip_w, const int* __restrict__ flag,
                          int* __restrict__ row_ptr, int* __restrict__ stb) {
  int e = blockIdx.x * 256 + threadIdx.x;
  if (e >= E_NUM) return;
  int h, t, b;
  load_edge(trip_w, e, flag[0], h, t, b);
  int pos = atomicAdd(&row_ptr[h], 1);
  stb[pos] = (t & 0xFFFF) | (b << 16);  // t < 40000 < 2^16, b < 10
}

// ---------------- emb0 = relu(rel_emb @ p1w + p1b) -> d_out (f32) ----------------

__global__ void k_emb0(const void* __restrict__ A, const int* __restrict__ flag,
                       const float* __restrict__ wbuf, float* __restrict__ emb) {
  int j = threadIdx.x & 63;
  int g = threadIdx.x >> 6;
  int r0 = blockIdx.x * 16 + g * 4;
  int f32 = flag[1];
  __shared__ float sA[16][64];
  for (int k = threadIdx.x; k < 1024; k += 256) {
    int rr = k >> 6, cc = k & 63;
    size_t idx = (size_t)(blockIdx.x * 16 + rr) * 64 + cc;
    sA[rr][cc] = f32 ? ((const float*)A)[idx] : b2f(((const bf16*)A)[idx]);
  }
  __syncthreads();
  const float* W = wbuf + W_P1W;
  float a[4] = {0.f, 0.f, 0.f, 0.f};
  int base = g * 4;
  for (int i = 0; i < 64; i++) {
    float w = W[i * 64 + j];
#pragma unroll
    for (int n = 0; n < 4; n++) a[n] = fmaf(sA[base + n][i], w, a[n]);
  }
  float bj = wbuf[W_P1B + j];
#pragma unroll
  for (int n = 0; n < 4; n++)
    emb[(size_t)(r0 + n) * 64 + j] = fmaxf(a[n] + bj, 0.f);
}

// ---------------- XM[r][0..63] = Xt row, [64..127] = Mt row ----------------

template <typename ST>
__global__ void k_xm(const float* __restrict__ emb, const float* __restrict__ wbuf, int l,
                     ST* __restrict__ XM) {
  int j = threadIdx.x & 63;
  int g = threadIdx.x >> 6;
  int r0 = blockIdx.x * 16 + g * 4;
  __shared__ float sE[16][64];
  for (int k = threadIdx.x; k < 1024; k += 256) {
    int rr = k >> 6, cc = k & 63;
    sE[rr][cc] = emb[(size_t)(blockIdx.x * 16 + rr) * 64 + cc];
  }
  __syncthreads();
  const float* pwb = wbuf + W_APW + l * 8192 + 4096;  // bottom 64 rows of proj
  const float* aw = wbuf + W_AW + l * 4096;
  float axt[4] = {0.f, 0.f, 0.f, 0.f};
  float amt[4] = {0.f, 0.f, 0.f, 0.f};
  int base = g * 4;
  for (int i = 0; i < 64; i++) {
    float wt = pwb[i * 64 + j];
    float wm = aw[i * 64 + j];
#pragma unroll
    for (int n = 0; n < 4; n++) {
      float e = sE[base + n][i];
      axt[n] = fmaf(e, wt, axt[n]);
      amt[n] = fmaf(e, wm, amt[n]);
    }
  }
  float abj = wbuf[W_AB + l * 64 + j];
#pragma unroll
  for (int n = 0; n < 4; n++) {
    size_t r = r0 + n;
    stv(XM, r * 128 + j, axt[n]);
    stv(XM, r * 128 + 64 + j, amt[n] + abj);
  }
}

// ---------------- edge kernel: one wave per head node ----------------
// Xh, Res computed in-kernel from own emb row (in-place safe: no cross-row emb reads).

template <typename ST>
static __device__ __forceinline__ float raw_logit_c(const int* __restrict__ stb,
                                                    const ST* __restrict__ XM,
                                                    const float* __restrict__ abin, float xh,
                                                    float av, int j, int lane, int hh) {
  int p = stb[j];
  int t = p & 0xFFFF;
  int b = p >> 16;
  float z = xh + ldv(XM, (size_t)t * 128 + lane);
  z = (z > 0.f) ? z : 0.2f * z;
  float v = z * av;
  v += __shfl_xor(v, 1);
  v += __shfl_xor(v, 2);
  v += __shfl_xor(v, 4);
  float ab = abin[b * 8 + hh];
  ab = (ab > 0.f) ? ab : 0.2f * ab;
  return v + ab;
}

template <typename ST>
__global__ void k_edge_c(const int* __restrict__ row_ptr, const int* __restrict__ stb,
                         const ST* __restrict__ XM, const float* __restrict__ wbuf, int l,
                         float* __restrict__ emb) {
  __shared__ float sraw[4][DEG_CAP][8];
  __shared__ float semb[4][64];
  int lane = threadIdx.x & 63;
  int w = threadIdx.x >> 6;
  int r = blockIdx.x * 4 + w;
  int hh = lane >> 3;
  const float* pwt = wbuf + W_APW + l * 8192;  // top 64 rows
  const float* rw = wbuf + W_RW + l * 4096;
  const float* abin = wbuf + W_ABIN + l * 80;

  semb[w][lane] = emb[(size_t)r * 64 + lane];
  __syncthreads();

  float xh = wbuf[W_APB + l * 64 + lane];
  float res = wbuf[W_RB + l * 64 + lane];
  for (int i = 0; i < 64; i++) {
    float e = semb[w][i];
    xh = fmaf(e, pwt[i * 64 + lane], xh);
    res = fmaf(e, rw[i * 64 + lane], res);
  }
  res = fmaxf(res, 0.f);
  float av = wbuf[W_AVEC + l * 64 + lane];

  int beg = (r == 0) ? 0 : row_ptr[r - 1];
  int end = row_ptr[r];

  // phase A: logits + max
  float m = -INFINITY;
  for (int j = beg; j < end; j++) {
    float raw = raw_logit_c(stb, XM, abin, xh, av, j, lane, hh);
    int idx = j - beg;
    if ((lane & 7) == 0 && idx < DEG_CAP) sraw[w][idx][hh] = raw;
    m = fmaxf(m, raw);
  }
  __builtin_amdgcn_wave_barrier();

  // phase B: sum of exp
  float s = 0.f;
  for (int j = beg; j < end; j++) {
    int idx = j - beg;
    float raw = (idx < DEG_CAP) ? sraw[w][idx][hh]
                                : raw_logit_c(stb, XM, abin, xh, av, j, lane, hh);
    s += __expf(raw - m);
  }
  float inv_s = 1.0f / (s + 1e-16f);

  // phase C: weighted accumulate of Mt[tail]
  float acc = 0.f;
  for (int j = beg; j < end; j++) {
    int p = stb[j];
    int t = p & 0xFFFF;
    int idx = j - beg;
    float raw = (idx < DEG_CAP) ? sraw[w][idx][hh]
                                : raw_logit_c(stb, XM, abin, xh, av, j, lane, hh);
    float beta = __expf(raw - m) * inv_s;
    acc = fmaf(ldv(XM, (size_t)t * 128 + 64 + lane), beta, acc);
  }

  emb[(size_t)r * 64 + lane] = fmaxf(acc, 0.f) + res;
}

// ---------------- Plan D: no XM, Xt/Mt via shfl-broadcast matvec (fallback) ----------------

static __device__ __forceinline__ float dotcol(const float* __restrict__ Wm, float val, int lane) {
  float acc = 0.f;
  for (int i = 0; i < 64; i++) acc = fmaf(__shfl(val, i), Wm[i * 64 + lane], acc);
  return acc;
}

template <typename TIN>
static __device__ __forceinline__ float raw_logit_d(const int* __restrict__ stb,
                                                    const TIN* __restrict__ emb_in,
                                                    const float* __restrict__ pwb,
                                                    const float* __restrict__ abin, float xh,
                                                    float av, int j, int lane, int hh) {
  int p = stb[j];
  int t = p & 0xFFFF;
  int b = p >> 16;
  float tv = ldv(emb_in, (size_t)t * 64 + lane);
  float z = xh + dotcol(pwb, tv, lane);
  z = (z > 0.f) ? z : 0.2f * z;
  float v = z * av;
  v += __shfl_xor(v, 1);
  v += __shfl_xor(v, 2);
  v += __shfl_xor(v, 4);
  float ab = abin[b * 8 + hh];
  ab = (ab > 0.f) ? ab : 0.2f * ab;
  return v + ab;
}

template <typename TIN, typename TOUT>
__global__ void k_edge_d(const int* __restrict__ row_ptr, const int* __restrict__ stb,
                         const float* __restrict__ wbuf, int l, const TIN* __restrict__ emb_in,
                         TOUT* __restrict__ emb_out) {
  __shared__ float sraw[4][DEG_CAP][8];
  __shared__ float semb[4][64];
  int lane = threadIdx.x & 63;
  int w = threadIdx.x >> 6;
  int r = blockIdx.x * 4 + w;
  int hh = lane >> 3;
  const float* pwt = wbuf + W_APW + l * 8192;
  const float* pwb = pwt + 4096;
  const float* aw = wbuf + W_AW + l * 4096;
  const float* rw = wbuf + W_RW + l * 4096;
  const float* abin = wbuf + W_ABIN + l * 80;

  semb[w][lane] = ldv(emb_in, (size_t)r * 64 + lane);
  __syncthreads();

  float xh = wbuf[W_APB + l * 64 + lane];
  float res = wbuf[W_RB + l * 64 + lane];
  for (int i = 0; i < 64; i++) {
    float e = semb[w][i];
    xh = fmaf(e, pwt[i * 64 + lane], xh);
    res = fmaf(e, rw[i * 64 + lane], res);
  }
  res = fmaxf(res, 0.f);
  float av = wbuf[W_AVEC + l * 64 + lane];
  float abl = wbuf[W_AB + l * 64 + lane];

  int beg = (r == 0) ? 0 : row_ptr[r - 1];
  int end = row_ptr[r];

  float m = -INFINITY;
  for (int j = beg; j < end; j++) {
    float raw = raw_logit_d(stb, emb_in, pwb, abin, xh, av, j, lane, hh);
    int idx = j - beg;
    if ((lane & 7) == 0 && idx < DEG_CAP) sraw[w][idx][hh] = raw;
    m = fmaxf(m, raw);
  }
  __builtin_amdgcn_wave_barrier();

  float s = 0.f;
  for (int j = beg; j < end; j++) {
    int idx = j - beg;
    float raw = (idx < DEG_CAP) ? sraw[w][idx][hh]
                                : raw_logit_d(stb, emb_in, pwb, abin, xh, av, j, lane, hh);
    s += __expf(raw - m);
  }
  float inv_s = 1.0f / (s + 1e-16f);

  float acc = 0.f;
  for (int j = beg; j < end; j++) {
    int p = stb[j];
    int t = p & 0xFFFF;
    int idx = j - beg;
    float raw = (idx < DEG_CAP) ? sraw[w][idx][hh]
                                : raw_logit_d(stb, emb_in, pwb, abin, xh, av, j, lane, hh);
    float beta = __expf(raw - m) * inv_s;
    float tv = ldv(emb_in, (size_t)t * 64 + lane);
    float mt = dotcol(aw, tv, lane) + abl;
    acc = fmaf(mt, beta, acc);
  }

  stv(emb_out, (size_t)r * 64 + lane, fmaxf(acc, 0.f) + res);
}

// ---------------- launch ----------------

extern "C" void kernel_launch(void* const* d_in, const int* in_sizes, int n_in,
                              void* d_out, int out_size, void* d_ws, size_t ws_size,
                              hipStream_t stream) {
  const unsigned int* trip_w = (const unsigned int*)d_in[0];
  const void* rel_emb = d_in[1];
  float* emb = (float*)d_out;  // f32 output; used as the live embedding buffer

  char* ws = (char*)d_ws;
  int* flag = (int*)ws;                      // 256 B
  float* wbuf = (float*)(ws + 256);          // 37632 f32 = 150528 B
  int* row_ptr = (int*)(ws + 256 + 150528);  // 40064 ints
  int* counts = row_ptr + 40064;             // 40000 ints
  int* stb = counts + 40000;                 // 500000 ints
  char* big = (char*)(stb + 500000);         // byte offset 2471040
  const size_t base_used = 2471040;
  const size_t needC32 = base_used + (size_t)R_NUM * 128 * 4;  // 22,951,040
  const size_t needC16 = base_used + (size_t)R_NUM * 128 * 2;  // 12,711,040
  const size_t needD = base_used + (size_t)R_NUM * 64 * 2;     //  7,591,040

  hipMemsetAsync(counts, 0, R_NUM * sizeof(int), stream);
  k_detect<<<1, 64, 0, stream>>>(trip_w, (const unsigned short*)rel_emb, flag);
  k_wconv<<<(W_END + 255) / 256, 256, 0, stream>>>(d_in[2], d_in[3], d_in[4], d_in[5], d_in[6],
                                                   d_in[7], d_in[8], d_in[9], d_in[10], d_in[11],
                                                   flag, wbuf);
  int eb_blocks = (E_NUM + 255) / 256;
  k_hist<<<eb_blocks, 256, 0, stream>>>(trip_w, flag, counts);
  k_scan<<<1, 1024, 0, stream>>>(counts, row_ptr);
  k_scatter<<<eb_blocks, 256, 0, stream>>>(trip_w, flag, row_ptr, stb);

  k_emb0<<<R_NUM / 16, 256, 0, stream>>>(rel_emb, flag, wbuf, emb);

  if (ws_size >= needC32) {
    float* XM = (float*)big;
    for (int l = 0; l < 2; l++) {
      k_xm<float><<<R_NUM / 16, 256, 0, stream>>>(emb, wbuf, l, XM);
      k_edge_c<float><<<R_NUM / 4, 256, 0, stream>>>(row_ptr, stb, XM, wbuf, l, emb);
    }
  } else if (ws_size >= needC16) {
    bf16* XM = (bf16*)big;
    for (int l = 0; l < 2; l++) {
      k_xm<bf16><<<R_NUM / 16, 256, 0, stream>>>(emb, wbuf, l, XM);
      k_edge_c<bf16><<<R_NUM / 4, 256, 0, stream>>>(row_ptr, stb, XM, wbuf, l, emb);
    }
  } else {
    bf16* embB = (bf16*)big;  // 5.12 MB ping buffer
    k_edge_d<float, bf16><<<R_NUM / 4, 256, 0, stream>>>(row_ptr, stb, wbuf, 0, emb, embB);
    k_edge_d<bf16, float><<<R_NUM / 4, 256, 0, stream>>>(row_ptr, stb, wbuf, 1, embB, emb);
  }
}

// Round 6
// 611.531 us; speedup vs baseline: 2.4401x; 2.4401x over previous
//
#include <hip/hip_runtime.h>
#include <hip/hip_bf16.h>

typedef __hip_bfloat16 bf16;

#define R_NUM 40000
#define E_NUM 500000
#define DEG_CAP 192

// wbuf layout (f32 element offsets)
#define W_P1W 0
#define W_P1B 4096
#define W_APW 4160    // 2*128*64
#define W_APB 20544   // 2*64
#define W_ABIN 20672  // 2*10*8
#define W_AVEC 20832  // 2*8*8
#define W_AW 20960    // 2*64*64
#define W_AB 29152
#define W_RW 29280
#define W_RB 37472
#define W_END 37600

static __device__ __forceinline__ float b2f(bf16 x) { return __bfloat162float(x); }
static __device__ __forceinline__ float ldv(const float* p, size_t i) { return p[i]; }
static __device__ __forceinline__ float ldv(const bf16* p, size_t i) { return __bfloat162float(p[i]); }
static __device__ __forceinline__ void stv(float* p, size_t i, float v) { p[i] = v; }
static __device__ __forceinline__ void stv(bf16* p, size_t i, float v) { p[i] = __float2bfloat16(v); }

// ---------------- runtime dtype detection (robustness) ----------------

__global__ void k_detect(const unsigned int* __restrict__ trip_w,
                         const unsigned short* __restrict__ emb_w, int* __restrict__ flag) {
  int lane = threadIdx.x;
  unsigned int acc = 0;
  for (int i = lane; i < 1024; i += 64) acc |= trip_w[2 * i + 1];
  int votes = 0;
  for (int i = lane; i < 2048; i += 64) {
    unsigned short u = emb_w[2 * i];
    int ex = (u >> 7) & 0xFF;
    if (ex >= 90 && ex <= 130) votes++;
  }
  for (int off = 1; off < 64; off <<= 1) {
    acc |= __shfl_xor(acc, off);
    votes += __shfl_xor(votes, off);
  }
  if (lane == 0) {
    flag[0] = (acc == 0) ? 1 : 0;
    flag[1] = (votes < 1024) ? 1 : 0;
  }
}

// ---------------- weights -> f32 scratch ----------------

__global__ void k_wconv(const void* p1w, const void* p1b, const void* apw, const void* apb,
                        const void* abin, const void* avec, const void* aw, const void* ab,
                        const void* rw, const void* rb, const int* __restrict__ flag,
                        float* __restrict__ wbuf) {
  int i = blockIdx.x * 256 + threadIdx.x;
  if (i >= W_END) return;
  const void* src;
  int off;
  if (i < W_P1B) { src = p1w; off = i - W_P1W; }
  else if (i < W_APW) { src = p1b; off = i - W_P1B; }
  else if (i < W_APB) { src = apw; off = i - W_APW; }
  else if (i < W_ABIN) { src = apb; off = i - W_APB; }
  else if (i < W_AVEC) { src = abin; off = i - W_ABIN; }
  else if (i < W_AW) { src = avec; off = i - W_AVEC; }
  else if (i < W_AB) { src = aw; off = i - W_AW; }
  else if (i < W_RW) { src = ab; off = i - W_AB; }
  else if (i < W_RB) { src = rw; off = i - W_RW; }
  else { src = rb; off = i - W_RB; }
  wbuf[i] = flag[1] ? ((const float*)src)[off] : b2f(((const bf16*)src)[off]);
}

// ---------------- edge decode ----------------

static __device__ __forceinline__ void load_edge(const unsigned int* __restrict__ w, int e,
                                                 int i64, int& h, int& t, int& b) {
  if (i64) {
    h = (int)w[6 * e + 0];
    t = (int)w[6 * e + 2];
    b = (int)w[6 * e + 4];
  } else {
    h = (int)w[3 * e + 0];
    t = (int)w[3 * e + 1];
    b = (int)w[3 * e + 2];
  }
}

// ---------------- counting sort by head ----------------

__global__ void k_hist(const unsigned int* __restrict__ trip_w, const int* __restrict__ flag,
                       int* __restrict__ counts) {
  int e = blockIdx.x * 256 + threadIdx.x;
  if (e >= E_NUM) return;
  int h, t, b;
  load_edge(trip_w, e, flag[0], h, t, b);
  atomicAdd(&counts[h], 1);
}

__global__ void k_scan(const int* __restrict__ counts, int* __restrict__ row_ptr) {
  __shared__ int sd[1024];
  int tid = threadIdx.x;
  int carry = 0;
  for (int base = 0; base < 40960; base += 1024) {
    int idx = base + tid;
    int v = (idx < R_NUM) ? counts[idx] : 0;
    sd[tid] = v;
    __syncthreads();
    for (int off = 1; off < 1024; off <<= 1) {
      int t = (tid >= off) ? sd[tid - off] : 0;
      __syncthreads();
      sd[tid] += t;
      __syncthreads();
    }
    if (idx < R_NUM) row_ptr[idx] = carry + sd[tid] - v;  // exclusive
    carry += sd[1023];
    __syncthreads();
  }
  if (tid == 0) row_ptr[R_NUM] = carry;
}

// scatter bumps row_ptr: afterwards row_ptr[r] == end(r); beg(r) = r ? row_ptr[r-1] : 0
__global__ void k_scatter(const unsigned int* __restrict__ trip_w, const int* __restrict__ flag,
                          int* __restrict__ row_ptr, int* __restrict__ stb) {
  int e = blockIdx.x * 256 + threadIdx.x;
  if (e >= E_NUM) return;
  int h, t, b;
  load_edge(trip_w, e, flag[0], h, t, b);
  int pos = atomicAdd(&row_ptr[h], 1);
  stb[pos] = (t & 0xFFFF) | (b << 16);  // t < 40000 < 2^16, b < 10
}

// ---------------- emb0 = relu(rel_emb @ p1w + p1b) -> d_out (f32) ----------------

__global__ void k_emb0(const void* __restrict__ A, const int* __restrict__ flag,
                       const float* __restrict__ wbuf, float* __restrict__ emb) {
  int j = threadIdx.x & 63;
  int g = threadIdx.x >> 6;
  int r0 = blockIdx.x * 16 + g * 4;
  int f32 = flag[1];
  __shared__ float sA[16][64];
  for (int k = threadIdx.x; k < 1024; k += 256) {
    int rr = k >> 6, cc = k & 63;
    size_t idx = (size_t)(blockIdx.x * 16 + rr) * 64 + cc;
    sA[rr][cc] = f32 ? ((const float*)A)[idx] : b2f(((const bf16*)A)[idx]);
  }
  __syncthreads();
  const float* W = wbuf + W_P1W;
  float a[4] = {0.f, 0.f, 0.f, 0.f};
  int base = g * 4;
  for (int i = 0; i < 64; i++) {
    float w = W[i * 64 + j];
#pragma unroll
    for (int n = 0; n < 4; n++) a[n] = fmaf(sA[base + n][i], w, a[n]);
  }
  float bj = wbuf[W_P1B + j];
#pragma unroll
  for (int n = 0; n < 4; n++)
    emb[(size_t)(r0 + n) * 64 + j] = fmaxf(a[n] + bj, 0.f);
}

// ---------------- XM2[r][j] = float2(Xt[r][j], Mt[r][j]) ----------------

__global__ void k_xm(const float* __restrict__ emb, const float* __restrict__ wbuf, int l,
                     float2* __restrict__ XM) {
  int j = threadIdx.x & 63;
  int g = threadIdx.x >> 6;
  int r0 = blockIdx.x * 16 + g * 4;
  __shared__ float sE[16][64];
  for (int k = threadIdx.x; k < 1024; k += 256) {
    int rr = k >> 6, cc = k & 63;
    sE[rr][cc] = emb[(size_t)(blockIdx.x * 16 + rr) * 64 + cc];
  }
  __syncthreads();
  const float* pwb = wbuf + W_APW + l * 8192 + 4096;  // bottom 64 rows of proj
  const float* aw = wbuf + W_AW + l * 4096;
  float axt[4] = {0.f, 0.f, 0.f, 0.f};
  float amt[4] = {0.f, 0.f, 0.f, 0.f};
  int base = g * 4;
  for (int i = 0; i < 64; i++) {
    float wt = pwb[i * 64 + j];
    float wm = aw[i * 64 + j];
#pragma unroll
    for (int n = 0; n < 4; n++) {
      float e = sE[base + n][i];
      axt[n] = fmaf(e, wt, axt[n]);
      amt[n] = fmaf(e, wm, amt[n]);
    }
  }
  float abj = wbuf[W_AB + l * 64 + j];
#pragma unroll
  for (int n = 0; n < 4; n++) {
    size_t r = r0 + n;
    XM[r * 64 + j] = make_float2(axt[n], amt[n] + abj);
  }
}

// ---------------- single-pass edge kernel: one wave per head node ----------------
// softmax without max-subtraction (logits tiny; shift-invariant):
//   out = (sum_j e_j * mt_j) / (sum_j e_j + 1e-16)
// stb entries preloaded per-lane and shfl-broadcast; XM gathers depth-2 pipelined.

__global__ void __launch_bounds__(256) k_edge1(const int* __restrict__ row_ptr,
                                               const int* __restrict__ stb,
                                               const float2* __restrict__ XM,
                                               const float* __restrict__ wbuf, int l,
                                               float* __restrict__ emb) {
  __shared__ float sab[80];  // leaky(abin[l]) table, [b][hh]
  int tid = threadIdx.x;
  int lane = tid & 63;
  int w = tid >> 6;
  int r = blockIdx.x * 4 + w;
  int hh = lane >> 3;
  if (tid < 80) {
    float a = wbuf[W_ABIN + l * 80 + tid];
    sab[tid] = (a > 0.f) ? a : 0.2f * a;
  }
  __syncthreads();

  const float* pwt = wbuf + W_APW + l * 8192;  // top 64 rows of proj
  const float* rw = wbuf + W_RW + l * 4096;

  float ev = emb[(size_t)r * 64 + lane];
  float xh = wbuf[W_APB + l * 64 + lane];
  float res = wbuf[W_RB + l * 64 + lane];
#pragma unroll
  for (int i = 0; i < 64; i++) {
    float e = __shfl(ev, i);
    xh = fmaf(e, pwt[i * 64 + lane], xh);
    res = fmaf(e, rw[i * 64 + lane], res);
  }
  res = fmaxf(res, 0.f);
  float av = wbuf[W_AVEC + l * 64 + lane];

  int beg = (r == 0) ? 0 : row_ptr[r - 1];
  int end = row_ptr[r];

  float num = 0.f, den = 0.f;
  for (int c = beg; c < end; c += 64) {
    int n = min(64, end - c);
    int pl = (c + lane < end) ? stb[c + lane] : 0;
    int p0 = __shfl(pl, 0);
    float2 xm0 = XM[(size_t)(p0 & 0xFFFF) * 64 + lane];
    for (int j = 0; j < n; j++) {
      int pj = p0;
      float2 xmj = xm0;
      if (j + 1 < n) {
        p0 = __shfl(pl, j + 1);
        xm0 = XM[(size_t)(p0 & 0xFFFF) * 64 + lane];
      }
      float z = xh + xmj.x;
      z = (z > 0.f) ? z : 0.2f * z;
      float v = z * av;
      v += __shfl_xor(v, 1);
      v += __shfl_xor(v, 2);
      v += __shfl_xor(v, 4);
      float e = __expf(v + sab[(pj >> 16) * 8 + hh]);
      den += e;
      num = fmaf(xmj.y, e, num);
    }
  }

  emb[(size_t)r * 64 + lane] = fmaxf(num / (den + 1e-16f), 0.f) + res;
}

// ---------------- Plan D fallback (tiny ws): per-edge recompute ----------------

static __device__ __forceinline__ float dotcol(const float* __restrict__ Wm, float val, int lane) {
  float acc = 0.f;
  for (int i = 0; i < 64; i++) acc = fmaf(__shfl(val, i), Wm[i * 64 + lane], acc);
  return acc;
}

template <typename TIN, typename TOUT>
__global__ void k_edge_d(const int* __restrict__ row_ptr, const int* __restrict__ stb,
                         const float* __restrict__ wbuf, int l, const TIN* __restrict__ emb_in,
                         TOUT* __restrict__ emb_out) {
  __shared__ float sab[80];
  int tid = threadIdx.x;
  int lane = tid & 63;
  int w = tid >> 6;
  int r = blockIdx.x * 4 + w;
  int hh = lane >> 3;
  if (tid < 80) {
    float a = wbuf[W_ABIN + l * 80 + tid];
    sab[tid] = (a > 0.f) ? a : 0.2f * a;
  }
  __syncthreads();
  const float* pwt = wbuf + W_APW + l * 8192;
  const float* pwb = pwt + 4096;
  const float* aw = wbuf + W_AW + l * 4096;
  const float* rw = wbuf + W_RW + l * 4096;

  float ev = ldv(emb_in, (size_t)r * 64 + lane);
  float xh = wbuf[W_APB + l * 64 + lane];
  float res = wbuf[W_RB + l * 64 + lane];
#pragma unroll
  for (int i = 0; i < 64; i++) {
    float e = __shfl(ev, i);
    xh = fmaf(e, pwt[i * 64 + lane], xh);
    res = fmaf(e, rw[i * 64 + lane], res);
  }
  res = fmaxf(res, 0.f);
  float av = wbuf[W_AVEC + l * 64 + lane];
  float abl = wbuf[W_AB + l * 64 + lane];

  int beg = (r == 0) ? 0 : row_ptr[r - 1];
  int end = row_ptr[r];
  float num = 0.f, den = 0.f;
  for (int j = beg; j < end; j++) {
    int p = stb[j];
    int t = p & 0xFFFF;
    float tv = ldv(emb_in, (size_t)t * 64 + lane);
    float z = xh + dotcol(pwb, tv, lane);
    z = (z > 0.f) ? z : 0.2f * z;
    float v = z * av;
    v += __shfl_xor(v, 1);
    v += __shfl_xor(v, 2);
    v += __shfl_xor(v, 4);
    float e = __expf(v + sab[(p >> 16) * 8 + hh]);
    den += e;
    float mt = dotcol(aw, tv, lane) + abl;
    num = fmaf(mt, e, num);
  }
  stv(emb_out, (size_t)r * 64 + lane, fmaxf(num / (den + 1e-16f), 0.f) + res);
}

// ---------------- launch ----------------

extern "C" void kernel_launch(void* const* d_in, const int* in_sizes, int n_in,
                              void* d_out, int out_size, void* d_ws, size_t ws_size,
                              hipStream_t stream) {
  const unsigned int* trip_w = (const unsigned int*)d_in[0];
  const void* rel_emb = d_in[1];
  float* emb = (float*)d_out;  // f32 output doubles as the live embedding buffer

  char* ws = (char*)d_ws;
  int* flag = (int*)ws;                      // 256 B
  float* wbuf = (float*)(ws + 256);          // 37632 f32
  int* row_ptr = (int*)(ws + 256 + 150528);  // 40064 ints
  int* counts = row_ptr + 40064;             // 40000 ints
  int* stb = counts + 40000;                 // 500000 ints
  char* big = (char*)(stb + 500000);         // byte offset 2471040
  const size_t base_used = 2471040;
  const size_t needC32 = base_used + (size_t)R_NUM * 128 * 4;  // 22,951,040 (proven to fit)

  hipMemsetAsync(counts, 0, R_NUM * sizeof(int), stream);
  k_detect<<<1, 64, 0, stream>>>(trip_w, (const unsigned short*)rel_emb, flag);
  k_wconv<<<(W_END + 255) / 256, 256, 0, stream>>>(d_in[2], d_in[3], d_in[4], d_in[5], d_in[6],
                                                   d_in[7], d_in[8], d_in[9], d_in[10], d_in[11],
                                                   flag, wbuf);
  int eb_blocks = (E_NUM + 255) / 256;
  k_hist<<<eb_blocks, 256, 0, stream>>>(trip_w, flag, counts);
  k_scan<<<1, 1024, 0, stream>>>(counts, row_ptr);
  k_scatter<<<eb_blocks, 256, 0, stream>>>(trip_w, flag, row_ptr, stb);

  k_emb0<<<R_NUM / 16, 256, 0, stream>>>(rel_emb, flag, wbuf, emb);

  if (ws_size >= needC32) {
    float2* XM = (float2*)big;
    for (int l = 0; l < 2; l++) {
      k_xm<<<R_NUM / 16, 256, 0, stream>>>(emb, wbuf, l, XM);
      k_edge1<<<R_NUM / 4, 256, 0, stream>>>(row_ptr, stb, XM, wbuf, l, emb);
    }
  } else {
    bf16* embB = (bf16*)big;  // 5.12 MB ping buffer
    k_edge_d<float, bf16><<<R_NUM / 4, 256, 0, stream>>>(row_ptr, stb, wbuf, 0, emb, embB);
    k_edge_d<bf16, float><<<R_NUM / 4, 256, 0, stream>>>(row_ptr, stb, wbuf, 1, embB, emb);
  }
}

// Round 7
// 421.984 us; speedup vs baseline: 3.5361x; 1.4492x over previous
//
#include <hip/hip_runtime.h>
#include <hip/hip_bf16.h>

typedef __hip_bfloat16 bf16;

#define R_NUM 40000
#define E_NUM 500000

// wbuf layout (f32 element offsets)
#define W_P1W 0
#define W_P1B 4096
#define W_APW 4160    // 2*128*64
#define W_APB 20544   // 2*64
#define W_ABIN 20672  // 2*10*8
#define W_AVEC 20832  // 2*8*8
#define W_AW 20960    // 2*64*64
#define W_AB 29152
#define W_RW 29280
#define W_RB 37472
#define W_END 37600

// ws byte offsets
#define O_FLAG 0
#define O_WBUF 256
#define O_ROWP 150784
#define O_CNTS 310784
#define O_TMP 470784
#define O_PART 634624
#define O_OFFS 634880
#define O_STB 635136
#define O_BIG 2635136
#define NEED_XM1 (O_BIG + 20480000)          // 23,115,136
#define NEED_XM2 (O_BIG + 2 * 20480000)      // 43,595,136
#define NEED_D (O_BIG + 5120000)             // 7,755,136

static __device__ __forceinline__ float b2f(bf16 x) { return __bfloat162float(x); }
static __device__ __forceinline__ float ldv(const float* p, size_t i) { return p[i]; }
static __device__ __forceinline__ float ldv(const bf16* p, size_t i) { return __bfloat162float(p[i]); }
static __device__ __forceinline__ void stv(float* p, size_t i, float v) { p[i] = v; }
static __device__ __forceinline__ void stv(bf16* p, size_t i, float v) { p[i] = __float2bfloat16(v); }

// ---------------- runtime dtype detection ----------------

__global__ void k_detect(const unsigned int* __restrict__ trip_w,
                         const unsigned short* __restrict__ emb_w, int* __restrict__ flag) {
  int lane = threadIdx.x;
  unsigned int acc = 0;
  for (int i = lane; i < 1024; i += 64) acc |= trip_w[2 * i + 1];
  int votes = 0;
  for (int i = lane; i < 2048; i += 64) {
    unsigned short u = emb_w[2 * i];
    int ex = (u >> 7) & 0xFF;
    if (ex >= 90 && ex <= 130) votes++;
  }
  for (int off = 1; off < 64; off <<= 1) {
    acc |= __shfl_xor(acc, off);
    votes += __shfl_xor(votes, off);
  }
  if (lane == 0) {
    flag[0] = (acc == 0) ? 1 : 0;
    flag[1] = (votes < 1024) ? 1 : 0;
  }
}

// ---------------- weights -> f32 scratch ----------------

__global__ void k_wconv(const void* p1w, const void* p1b, const void* apw, const void* apb,
                        const void* abin, const void* avec, const void* aw, const void* ab,
                        const void* rw, const void* rb, const int* __restrict__ flag,
                        float* __restrict__ wbuf) {
  int i = blockIdx.x * 256 + threadIdx.x;
  if (i >= W_END) return;
  const void* src;
  int off;
  if (i < W_P1B) { src = p1w; off = i - W_P1W; }
  else if (i < W_APW) { src = p1b; off = i - W_P1B; }
  else if (i < W_APB) { src = apw; off = i - W_APW; }
  else if (i < W_ABIN) { src = apb; off = i - W_APB; }
  else if (i < W_AVEC) { src = abin; off = i - W_ABIN; }
  else if (i < W_AW) { src = avec; off = i - W_AVEC; }
  else if (i < W_AB) { src = aw; off = i - W_AW; }
  else if (i < W_RW) { src = ab; off = i - W_AB; }
  else if (i < W_RB) { src = rw; off = i - W_RW; }
  else { src = rb; off = i - W_RB; }
  wbuf[i] = flag[1] ? ((const float*)src)[off] : b2f(((const bf16*)src)[off]);
}

// ---------------- edge decode ----------------

static __device__ __forceinline__ void load_edge(const unsigned int* __restrict__ w, int e,
                                                 int i64, int& h, int& t, int& b) {
  if (i64) {
    h = (int)w[6 * e + 0];
    t = (int)w[6 * e + 2];
    b = (int)w[6 * e + 4];
  } else {
    h = (int)w[3 * e + 0];
    t = (int)w[3 * e + 1];
    b = (int)w[3 * e + 2];
  }
}

// ---------------- counting sort by head ----------------

__global__ void k_hist(const unsigned int* __restrict__ trip_w, const int* __restrict__ flag,
                       int* __restrict__ counts) {
  int e = blockIdx.x * 256 + threadIdx.x;
  if (e >= E_NUM) return;
  int h, t, b;
  load_edge(trip_w, e, flag[0], h, t, b);
  atomicAdd(&counts[h], 1);
}

// 3-kernel scan: block-local inclusive, partial scan, add-offsets (exclusive out)
__global__ void k_scan_a(const int* __restrict__ counts, int* __restrict__ tmp,
                         int* __restrict__ partial) {
  __shared__ int sd[1024];
  int tid = threadIdx.x;
  int idx = blockIdx.x * 1024 + tid;
  int v = (idx < R_NUM) ? counts[idx] : 0;
  sd[tid] = v;
  __syncthreads();
  for (int off = 1; off < 1024; off <<= 1) {
    int t = (tid >= off) ? sd[tid - off] : 0;
    __syncthreads();
    sd[tid] += t;
    __syncthreads();
  }
  if (idx < R_NUM) tmp[idx] = sd[tid];
  if (tid == 1023) partial[blockIdx.x] = sd[1023];
}

__global__ void k_scan_b(const int* __restrict__ partial, int* __restrict__ offs) {
  int lane = threadIdx.x;
  int p = (lane < 40) ? partial[lane] : 0;
  int x = p;
  for (int d = 1; d < 64; d <<= 1) {
    int y = __shfl_up(x, d);
    if (lane >= d) x += y;
  }
  if (lane < 40) offs[lane] = x - p;  // exclusive block offset
}

__global__ void k_scan_c(const int* __restrict__ counts, const int* __restrict__ tmp,
                         const int* __restrict__ offs, int* __restrict__ row_ptr) {
  int idx = blockIdx.x * 1024 + threadIdx.x;
  if (idx < R_NUM) row_ptr[idx] = tmp[idx] - counts[idx] + offs[blockIdx.x];
}

// scatter bumps row_ptr: afterwards row_ptr[r] == end(r); beg(r) = r ? row_ptr[r-1] : 0
__global__ void k_scatter(const unsigned int* __restrict__ trip_w, const int* __restrict__ flag,
                          int* __restrict__ row_ptr, int* __restrict__ stb) {
  int e = blockIdx.x * 256 + threadIdx.x;
  if (e >= E_NUM) return;
  int h, t, b;
  load_edge(trip_w, e, flag[0], h, t, b);
  int pos = atomicAdd(&row_ptr[h], 1);
  stb[pos] = (t & 0xFFFF) | (b << 16);
}

// ---------------- fused emb0 + (optional) layer-0 XM ----------------
// emb0 = relu(rel_emb @ p1w + p1b); XM[r][j] = (Xt, Mt) for layer 0.

__global__ void k_emb0xm(const void* __restrict__ A, const int* __restrict__ flag,
                         const float* __restrict__ wbuf, float* __restrict__ emb,
                         float2* __restrict__ XM, int write_xm) {
  int j = threadIdx.x & 63;
  int g = threadIdx.x >> 6;
  int r0 = blockIdx.x * 16 + g * 4;
  int f32 = flag[1];
  __shared__ float sA[16][64];
  for (int k = threadIdx.x; k < 1024; k += 256) {
    int rr = k >> 6, cc = k & 63;
    size_t idx = (size_t)(blockIdx.x * 16 + rr) * 64 + cc;
    sA[rr][cc] = f32 ? ((const float*)A)[idx] : b2f(((const bf16*)A)[idx]);
  }
  __syncthreads();
  const float* W = wbuf + W_P1W;
  float a[4] = {0.f, 0.f, 0.f, 0.f};
  int base = g * 4;
  for (int i = 0; i < 64; i++) {
    float w = W[i * 64 + j];
#pragma unroll
    for (int n = 0; n < 4; n++) a[n] = fmaf(sA[base + n][i], w, a[n]);
  }
  float bj = wbuf[W_P1B + j];
#pragma unroll
  for (int n = 0; n < 4; n++) {
    a[n] = fmaxf(a[n] + bj, 0.f);
    emb[(size_t)(r0 + n) * 64 + j] = a[n];
  }
  if (!write_xm) return;
  // phase 2: overwrite own rows of sA with emb0, then compute layer-0 Xt/Mt
  __syncthreads();
#pragma unroll
  for (int n = 0; n < 4; n++) sA[base + n][j] = a[n];
  __syncthreads();
  const float* pwb = wbuf + W_APW + 4096;  // layer-0 bottom proj rows
  const float* aw = wbuf + W_AW;
  float axt[4] = {0.f, 0.f, 0.f, 0.f};
  float amt[4] = {0.f, 0.f, 0.f, 0.f};
  for (int i = 0; i < 64; i++) {
    float wt = pwb[i * 64 + j];
    float wm = aw[i * 64 + j];
#pragma unroll
    for (int n = 0; n < 4; n++) {
      float e = sA[base + n][i];
      axt[n] = fmaf(e, wt, axt[n]);
      amt[n] = fmaf(e, wm, amt[n]);
    }
  }
  float abj = wbuf[W_AB + j];
#pragma unroll
  for (int n = 0; n < 4; n++)
    XM[(size_t)(r0 + n) * 64 + j] = make_float2(axt[n], amt[n] + abj);
}

// ---------------- standalone XM (single-buffer fallback path) ----------------

__global__ void k_xm(const float* __restrict__ emb, const float* __restrict__ wbuf, int l,
                     float2* __restrict__ XM) {
  int j = threadIdx.x & 63;
  int g = threadIdx.x >> 6;
  int r0 = blockIdx.x * 16 + g * 4;
  __shared__ float sE[16][64];
  for (int k = threadIdx.x; k < 1024; k += 256) {
    int rr = k >> 6, cc = k & 63;
    sE[rr][cc] = emb[(size_t)(blockIdx.x * 16 + rr) * 64 + cc];
  }
  __syncthreads();
  const float* pwb = wbuf + W_APW + l * 8192 + 4096;
  const float* aw = wbuf + W_AW + l * 4096;
  float axt[4] = {0.f, 0.f, 0.f, 0.f};
  float amt[4] = {0.f, 0.f, 0.f, 0.f};
  int base = g * 4;
  for (int i = 0; i < 64; i++) {
    float wt = pwb[i * 64 + j];
    float wm = aw[i * 64 + j];
#pragma unroll
    for (int n = 0; n < 4; n++) {
      float e = sE[base + n][i];
      axt[n] = fmaf(e, wt, axt[n]);
      amt[n] = fmaf(e, wm, amt[n]);
    }
  }
  float abj = wbuf[W_AB + l * 64 + j];
#pragma unroll
  for (int n = 0; n < 4; n++)
    XM[(size_t)(r0 + n) * 64 + j] = make_float2(axt[n], amt[n] + abj);
}

// ---------------- edge kernel: 4 rows/wave, window-8 prefetch ----------------
// WXM: epilogue also produces the NEXT layer's XM row (row-local, race-free).

template <bool WXM>
__global__ void __launch_bounds__(256) k_edge_f(const int* __restrict__ row_ptr,
                                                const int* __restrict__ stb,
                                                const float2* __restrict__ XM,
                                                const float* __restrict__ wbuf, int l,
                                                float* __restrict__ emb,
                                                float2* __restrict__ XMout) {
  __shared__ float sab[80];
  int tid = threadIdx.x;
  int lane = tid & 63;
  int w = tid >> 6;
  int hh = lane >> 3;
  if (tid < 80) {
    float a = wbuf[W_ABIN + l * 80 + tid];
    sab[tid] = (a > 0.f) ? a : 0.2f * a;
  }
  __syncthreads();

  const float* pwt = wbuf + W_APW + l * 8192;  // layer-l top proj
  const float* rwp = wbuf + W_RW + l * 4096;
  const float* pwb1 = wbuf + W_APW + 8192 + 4096;  // layer-1 bottom proj
  const float* aw1 = wbuf + W_AW + 4096;
  float av = wbuf[W_AVEC + l * 64 + lane];
  float xh0 = wbuf[W_APB + l * 64 + lane];
  float res0 = wbuf[W_RB + l * 64 + lane];
  float ab1 = WXM ? wbuf[W_AB + 64 + lane] : 0.f;

  int r0 = blockIdx.x * 16 + w * 4;
  for (int rr = 0; rr < 4; rr++) {
    int r = r0 + rr;
    float ev = emb[(size_t)r * 64 + lane];
    float xh = xh0, res = res0;
#pragma unroll 16
    for (int i = 0; i < 64; i++) {
      float e = __shfl(ev, i);
      xh = fmaf(e, pwt[i * 64 + lane], xh);
      res = fmaf(e, rwp[i * 64 + lane], res);
    }
    res = fmaxf(res, 0.f);

    int beg = (r == 0) ? 0 : row_ptr[r - 1];
    int end = row_ptr[r];
    float num = 0.f, den = 0.f;
    for (int c = beg; c < end; c += 64) {
      int nc = min(64, end - c);
      int pl = (c + lane < end) ? stb[c + lane] : 0;
      for (int wb = 0; wb < nc; wb += 8) {
        int wn = min(8, nc - wb);
        float2 xmv[8];
        int pk[8];
        if (wn == 8) {
#pragma unroll
          for (int k = 0; k < 8; k++) {
            pk[k] = __shfl(pl, wb + k);
            xmv[k] = XM[(size_t)(pk[k] & 0xFFFF) * 64 + lane];
          }
#pragma unroll
          for (int k = 0; k < 8; k++) {
            float z = xh + xmv[k].x;
            z = (z > 0.f) ? z : 0.2f * z;
            float v = z * av;
            v += __shfl_xor(v, 1);
            v += __shfl_xor(v, 2);
            v += __shfl_xor(v, 4);
            float e = __expf(v + sab[(pk[k] >> 16) * 8 + hh]);
            den += e;
            num = fmaf(xmv[k].y, e, num);
          }
        } else {
#pragma unroll
          for (int k = 0; k < 8; k++) {
            if (k < wn) {
              pk[k] = __shfl(pl, wb + k);
              xmv[k] = XM[(size_t)(pk[k] & 0xFFFF) * 64 + lane];
            }
          }
#pragma unroll
          for (int k = 0; k < 8; k++) {
            if (k < wn) {
              float z = xh + xmv[k].x;
              z = (z > 0.f) ? z : 0.2f * z;
              float v = z * av;
              v += __shfl_xor(v, 1);
              v += __shfl_xor(v, 2);
              v += __shfl_xor(v, 4);
              float e = __expf(v + sab[(pk[k] >> 16) * 8 + hh]);
              den += e;
              num = fmaf(xmv[k].y, e, num);
            }
          }
        }
      }
    }

    float o = fmaxf(num / (den + 1e-16f), 0.f) + res;
    emb[(size_t)r * 64 + lane] = o;
    if (WXM) {
      float xt = 0.f, mt = ab1;
#pragma unroll 16
      for (int i = 0; i < 64; i++) {
        float e = __shfl(o, i);
        xt = fmaf(e, pwb1[i * 64 + lane], xt);
        mt = fmaf(e, aw1[i * 64 + lane], mt);
      }
      XMout[(size_t)r * 64 + lane] = make_float2(xt, mt);
    }
  }
}

// ---------------- Plan D fallback (tiny ws): per-edge recompute ----------------

static __device__ __forceinline__ float dotcol(const float* __restrict__ Wm, float val, int lane) {
  float acc = 0.f;
  for (int i = 0; i < 64; i++) acc = fmaf(__shfl(val, i), Wm[i * 64 + lane], acc);
  return acc;
}

template <typename TIN, typename TOUT>
__global__ void k_edge_d(const int* __restrict__ row_ptr, const int* __restrict__ stb,
                         const float* __restrict__ wbuf, int l, const TIN* __restrict__ emb_in,
                         TOUT* __restrict__ emb_out) {
  __shared__ float sab[80];
  int tid = threadIdx.x;
  int lane = tid & 63;
  int w = tid >> 6;
  int r = blockIdx.x * 4 + w;
  int hh = lane >> 3;
  if (tid < 80) {
    float a = wbuf[W_ABIN + l * 80 + tid];
    sab[tid] = (a > 0.f) ? a : 0.2f * a;
  }
  __syncthreads();
  const float* pwt = wbuf + W_APW + l * 8192;
  const float* pwb = pwt + 4096;
  const float* aw = wbuf + W_AW + l * 4096;
  const float* rw = wbuf + W_RW + l * 4096;

  float ev = ldv(emb_in, (size_t)r * 64 + lane);
  float xh = wbuf[W_APB + l * 64 + lane];
  float res = wbuf[W_RB + l * 64 + lane];
  for (int i = 0; i < 64; i++) {
    float e = __shfl(ev, i);
    xh = fmaf(e, pwt[i * 64 + lane], xh);
    res = fmaf(e, rw[i * 64 + lane], res);
  }
  res = fmaxf(res, 0.f);
  float av = wbuf[W_AVEC + l * 64 + lane];
  float abl = wbuf[W_AB + l * 64 + lane];

  int beg = (r == 0) ? 0 : row_ptr[r - 1];
  int end = row_ptr[r];
  float num = 0.f, den = 0.f;
  for (int j = beg; j < end; j++) {
    int p = stb[j];
    int t = p & 0xFFFF;
    float tv = ldv(emb_in, (size_t)t * 64 + lane);
    float z = xh + dotcol(pwb, tv, lane);
    z = (z > 0.f) ? z : 0.2f * z;
    float v = z * av;
    v += __shfl_xor(v, 1);
    v += __shfl_xor(v, 2);
    v += __shfl_xor(v, 4);
    float e = __expf(v + sab[(p >> 16) * 8 + hh]);
    den += e;
    float mt = dotcol(aw, tv, lane) + abl;
    num = fmaf(mt, e, num);
  }
  stv(emb_out, (size_t)r * 64 + lane, fmaxf(num / (den + 1e-16f), 0.f) + res);
}

// ---------------- launch ----------------

extern "C" void kernel_launch(void* const* d_in, const int* in_sizes, int n_in,
                              void* d_out, int out_size, void* d_ws, size_t ws_size,
                              hipStream_t stream) {
  const unsigned int* trip_w = (const unsigned int*)d_in[0];
  const void* rel_emb = d_in[1];
  float* emb = (float*)d_out;  // f32 output doubles as live embedding buffer

  char* ws = (char*)d_ws;
  int* flag = (int*)(ws + O_FLAG);
  float* wbuf = (float*)(ws + O_WBUF);
  int* row_ptr = (int*)(ws + O_ROWP);
  int* counts = (int*)(ws + O_CNTS);
  int* tmp = (int*)(ws + O_TMP);
  int* partial = (int*)(ws + O_PART);
  int* offs = (int*)(ws + O_OFFS);
  int* stb = (int*)(ws + O_STB);
  char* big = ws + O_BIG;

  hipMemsetAsync(counts, 0, R_NUM * sizeof(int), stream);
  k_detect<<<1, 64, 0, stream>>>(trip_w, (const unsigned short*)rel_emb, flag);
  k_wconv<<<(W_END + 255) / 256, 256, 0, stream>>>(d_in[2], d_in[3], d_in[4], d_in[5], d_in[6],
                                                   d_in[7], d_in[8], d_in[9], d_in[10], d_in[11],
                                                   flag, wbuf);
  int eb_blocks = (E_NUM + 255) / 256;
  k_hist<<<eb_blocks, 256, 0, stream>>>(trip_w, flag, counts);
  k_scan_a<<<40, 1024, 0, stream>>>(counts, tmp, partial);
  k_scan_b<<<1, 64, 0, stream>>>(partial, offs);
  k_scan_c<<<40, 1024, 0, stream>>>(counts, tmp, offs, row_ptr);
  k_scatter<<<eb_blocks, 256, 0, stream>>>(trip_w, flag, row_ptr, stb);

  if (ws_size >= NEED_XM2) {
    float2* XMa = (float2*)big;
    float2* XMb = XMa + (size_t)R_NUM * 64;
    k_emb0xm<<<R_NUM / 16, 256, 0, stream>>>(rel_emb, flag, wbuf, emb, XMa, 1);
    k_edge_f<true><<<R_NUM / 16, 256, 0, stream>>>(row_ptr, stb, XMa, wbuf, 0, emb, XMb);
    k_edge_f<false><<<R_NUM / 16, 256, 0, stream>>>(row_ptr, stb, XMb, wbuf, 1, emb, nullptr);
  } else if (ws_size >= NEED_XM1) {
    float2* XM = (float2*)big;
    k_emb0xm<<<R_NUM / 16, 256, 0, stream>>>(rel_emb, flag, wbuf, emb, XM, 1);
    k_edge_f<false><<<R_NUM / 16, 256, 0, stream>>>(row_ptr, stb, XM, wbuf, 0, emb, nullptr);
    k_xm<<<R_NUM / 16, 256, 0, stream>>>(emb, wbuf, 1, XM);
    k_edge_f<false><<<R_NUM / 16, 256, 0, stream>>>(row_ptr, stb, XM, wbuf, 1, emb, nullptr);
  } else {
    k_emb0xm<<<R_NUM / 16, 256, 0, stream>>>(rel_emb, flag, wbuf, emb, nullptr, 0);
    bf16* embB = (bf16*)big;
    k_edge_d<float, bf16><<<R_NUM / 4, 256, 0, stream>>>(row_ptr, stb, wbuf, 0, emb, embB);
    k_edge_d<bf16, float><<<R_NUM / 4, 256, 0, stream>>>(row_ptr, stb, wbuf, 1, embB, emb);
  }
}